// Round 9
// baseline (5922.152 us; speedup 1.0000x reference)
//
#include <hip/hip_runtime.h>

#define NPTS 4096
#define NPT  1024
#define BATCH 16

// ---------------------------------------------------------------------------
// DPP helpers.
// ---------------------------------------------------------------------------
template <int CTRL>
__device__ __forceinline__ void dpp_keymax(unsigned long long& key)
{
    const int klo = (int)(unsigned int)key;
    const int khi = (int)(unsigned int)(key >> 32);
    const int nlo = __builtin_amdgcn_update_dpp(0, klo, CTRL, 0xF, 0xF, false);
    const int nhi = __builtin_amdgcn_update_dpp(0, khi, CTRL, 0xF, 0xF, false);
    const unsigned long long ok =
        ((unsigned long long)(unsigned int)nhi << 32) | (unsigned int)nlo;
    key = (ok > key) ? ok : key;
}

template <int CTRL>
__device__ __forceinline__ void dpp_keymax_xyz(unsigned long long& key,
                                               float& x, float& y, float& z)
{
    const int klo = (int)(unsigned int)key;
    const int khi = (int)(unsigned int)(key >> 32);
    const int nlo = __builtin_amdgcn_update_dpp(0, klo, CTRL, 0xF, 0xF, false);
    const int nhi = __builtin_amdgcn_update_dpp(0, khi, CTRL, 0xF, 0xF, false);
    const int nx  = __builtin_amdgcn_update_dpp(0, __float_as_int(x), CTRL, 0xF, 0xF, false);
    const int ny  = __builtin_amdgcn_update_dpp(0, __float_as_int(y), CTRL, 0xF, 0xF, false);
    const int nz  = __builtin_amdgcn_update_dpp(0, __float_as_int(z), CTRL, 0xF, 0xF, false);
    const unsigned long long ok =
        ((unsigned long long)(unsigned int)nhi << 32) | (unsigned int)nlo;
    const bool gt = ok > key;
    key = gt ? ok : key;
    x = gt ? __int_as_float(nx) : x;
    y = gt ? __int_as_float(ny) : y;
    z = gt ? __int_as_float(nz) : z;
}

// xor-1 lane exchange at VALU speed (quad_perm [1,0,3,2])
__device__ __forceinline__ float shflx1(float x)
{
    return __int_as_float(__builtin_amdgcn_update_dpp(
        0, __float_as_int(x), 0xB1, 0xF, 0xF, false));
}

// ---------------------------------------------------------------------------
// Farthest point sampling (unchanged from round 7).
// ---------------------------------------------------------------------------
__global__ __launch_bounds__(256) void fps_kernel(
    const float* __restrict__ xyz,
    float* __restrict__ out_nxyz,
    float* __restrict__ out_idxf)
{
    __shared__ float sx[NPTS], sy[NPTS], sz[NPTS];
    __shared__ float4 pr0[2][4];
    __shared__ float  pr1[2][4];
    __shared__ int sidx[NPT];

    const int tid  = threadIdx.x;
    const int b    = blockIdx.x;
    const int lane = tid & 63;
    const int wid  = tid >> 6;

    const float* bx = xyz + (size_t)b * NPTS * 3;
    for (int p = tid; p < NPTS; p += 256) {
        sx[p] = bx[3 * p];
        sy[p] = bx[3 * p + 1];
        sz[p] = bx[3 * p + 2];
    }
    if (tid == 0) sidx[0] = 0;
    __syncthreads();

    float rx[16], ry[16], rz[16], dist[16];
#pragma unroll
    for (int j = 0; j < 16; ++j) {
        const int p = tid + j * 256;
        rx[j] = sx[p];
        ry[j] = sy[p];
        rz[j] = sz[p];
        dist[j] = 1e10f;
    }

    float lx = sx[0], ly = sy[0], lz = sz[0];

    for (int step = 1; step < NPT; ++step) {
        float bv = -1.0f;
        int   bp = 0;
#pragma unroll
        for (int j = 0; j < 16; ++j) {
            const int p = tid + j * 256;
            const float dx = __fsub_rn(rx[j], lx);
            const float dy = __fsub_rn(ry[j], ly);
            const float dz = __fsub_rn(rz[j], lz);
            const float d  = __fadd_rn(__fadd_rn(__fmul_rn(dx, dx), __fmul_rn(dy, dy)),
                                       __fmul_rn(dz, dz));
            const float nd = fminf(dist[j], d);
            dist[j] = nd;
            const bool gt = nd > bv;
            bv = gt ? nd : bv;
            bp = gt ? p : bp;
        }
        unsigned long long key =
            ((unsigned long long)__float_as_uint(bv) << 32) |
            (unsigned int)(~bp);

        dpp_keymax<0x111>(key);   // row_shr:1
        dpp_keymax<0x112>(key);   // row_shr:2
        dpp_keymax<0x114>(key);   // row_shr:4
        dpp_keymax<0x118>(key);   // row_shr:8
        dpp_keymax<0x142>(key);   // row_bcast15
        dpp_keymax<0x143>(key);   // row_bcast31 -> lane63 = wave max

        const int par = step & 1;
        if (lane == 63) {
            const int wix = (int)(~(unsigned int)key);
            pr0[par][wid] = make_float4(
                __int_as_float((int)(unsigned int)key),
                __int_as_float((int)(unsigned int)(key >> 32)),
                sx[wix], sy[wix]);
            pr1[par][wid] = sz[wix];
        }
        __syncthreads();

        const float4 r  = pr0[par][lane & 3];
        const float  rzz = pr1[par][lane & 3];
        unsigned long long gkey =
            ((unsigned long long)(unsigned int)__float_as_int(r.y) << 32) |
            (unsigned int)__float_as_int(r.x);
        float gx = r.z, gy = r.w, gz = rzz;
        dpp_keymax_xyz<0xB1>(gkey, gx, gy, gz);   // quad_perm xor1
        dpp_keymax_xyz<0x4E>(gkey, gx, gy, gz);   // quad_perm xor2

        lx = gx; ly = gy; lz = gz;
        if (tid == 0) sidx[step] = (int)(~(unsigned int)gkey);
    }
    __syncthreads();

    for (int s = tid; s < NPT; s += 256) {
        const int ix = sidx[s];
        out_idxf[b * NPT + s] = (float)ix;
        out_nxyz[(size_t)(b * NPT + s) * 3 + 0] = sx[ix];
        out_nxyz[(size_t)(b * NPT + s) * 3 + 1] = sy[ix];
        out_nxyz[(size_t)(b * NPT + s) * 3 + 2] = sz[ix];
    }
}

// ---------------------------------------------------------------------------
// PAIR-SPLIT SA kernel (K = 32 or 64): 2 lanes per neighbor, lane bit0 = h
// (channel half). All activations register-resident with static indices;
// cross-half exchange via DPP quad_perm xor1 (VALU speed, no LDS).
// Per-lane live set ~100 regs -> no AGPR paging, no spills.
// Per output channel the fmaf chain is c-ascending == reference bit-exact.
// ---------------------------------------------------------------------------
template <int K, int F0, int F1, int F2, int CH_OFF>
__global__ __launch_bounds__(256) void sa_pair_kernel(
    const float* __restrict__ xyz,
    const float* __restrict__ points,
    const float* __restrict__ newxyz,
    const float* __restrict__ w0,
    const float* __restrict__ w1,
    const float* __restrict__ w2,
    float* __restrict__ out1,
    float r2)
{
    constexpr int WQ  = K / 32;          // waves per query
    constexpr int NQ  = 4 / WQ;          // queries per block
    constexpr int F0h = F0 / 2, F1h = F1 / 2, F2h = F2 / 2;

    __shared__ int   slist[NQ * K];
    __shared__ int   scnt[NQ];
    __shared__ float pool[NQ][WQ][2][F2h];

    const int tid    = threadIdx.x;
    const int lane   = tid & 63;
    const int wid    = tid >> 6;
    const int qlocal = wid / WQ;
    const int wq     = wid % WQ;
    const int h      = lane & 1;          // channel half
    const int nbl    = lane >> 1;         // neighbor within wave (0..31)
    const int slot   = wq * 32 + nbl;     // neighbor slot (< K)
    const int qid    = blockIdx.x * NQ + qlocal;
    const int b      = qid >> 10;

    const float qx = newxyz[(size_t)qid * 3 + 0];
    const float qy = newxyz[(size_t)qid * 3 + 1];
    const float qz = newxyz[(size_t)qid * 3 + 2];
    const float* bxyz = xyz + (size_t)b * NPTS * 3;

    // ---- ball query: wave wq==0 of each query scans (first-K ascending) ----
    if (wq == 0) {
        int cnt = 0;
        for (int c0 = 0; c0 < NPTS && cnt < K; c0 += 64) {
            const int p = c0 + lane;
            const float dx = __fsub_rn(qx, bxyz[3 * p]);
            const float dy = __fsub_rn(qy, bxyz[3 * p + 1]);
            const float dz = __fsub_rn(qz, bxyz[3 * p + 2]);
            const float d2 = __fadd_rn(__fadd_rn(__fmul_rn(dx, dx), __fmul_rn(dy, dy)),
                                       __fmul_rn(dz, dz));
            const bool hit = d2 < r2;
            const unsigned long long bal = __ballot(hit);
            const int pre = __popcll(bal & ((1ULL << lane) - 1ULL));
            const int pos = cnt + pre;
            if (hit && pos < K) slist[qlocal * K + pos] = p;
            cnt += (int)__popcll(bal);
        }
        if (lane == 0) scnt[qlocal] = (cnt < K) ? cnt : K;
    }
    __syncthreads();

    const int cn  = scnt[qlocal];
    const int nbr = slist[qlocal * K + ((slot < cn) ? slot : 0)];

    // ---- gather 19 inputs into registers (both halves duplicate) ----
    float a0r[19];
    {
        const float4* prow = (const float4*)(points + ((size_t)b * NPTS + nbr) * 16);
        const float4 p0 = prow[0], p1 = prow[1], p2 = prow[2], p3 = prow[3];
        a0r[0]  = p0.x; a0r[1]  = p0.y; a0r[2]  = p0.z; a0r[3]  = p0.w;
        a0r[4]  = p1.x; a0r[5]  = p1.y; a0r[6]  = p1.z; a0r[7]  = p1.w;
        a0r[8]  = p2.x; a0r[9]  = p2.y; a0r[10] = p2.z; a0r[11] = p2.w;
        a0r[12] = p3.x; a0r[13] = p3.y; a0r[14] = p3.z; a0r[15] = p3.w;
        a0r[16] = __fsub_rn(bxyz[3 * nbr],     qx);
        a0r[17] = __fsub_rn(bxyz[3 * nbr + 1], qy);
        a0r[18] = __fsub_rn(bxyz[3 * nbr + 2], qz);
    }

    // ---- layer 1: channels [h*F0h, h*F0h+F0h) ----
    float h0[F0h];
#pragma unroll
    for (int j = 0; j < F0h; ++j) h0[j] = 0.0f;
#pragma unroll
    for (int c = 0; c < 19; ++c) {
        const float xc = a0r[c];
        const float4* __restrict__ wr =
            (const float4*)(w0 + (size_t)c * F0 + h * F0h);
#pragma unroll
        for (int j4 = 0; j4 < F0h / 4; ++j4) {
            const float4 w = wr[j4];
            h0[4 * j4 + 0] = fmaf(xc, w.x, h0[4 * j4 + 0]);
            h0[4 * j4 + 1] = fmaf(xc, w.y, h0[4 * j4 + 1]);
            h0[4 * j4 + 2] = fmaf(xc, w.z, h0[4 * j4 + 2]);
            h0[4 * j4 + 3] = fmaf(xc, w.w, h0[4 * j4 + 3]);
        }
    }
#pragma unroll
    for (int j = 0; j < F0h; ++j) h0[j] = fmaxf(h0[j], 0.0f);

    // ---- layer 2: xc via DPP xor1 exchange; channels [h*F1h, +F1h) ----
    float acc1[F1h];
#pragma unroll
    for (int j = 0; j < F1h; ++j) acc1[j] = 0.0f;
#pragma unroll
    for (int c = 0; c < F0; ++c) {
        const float mine = h0[c % F0h];
        const float oth  = shflx1(mine);
        const float xc   = ((c / F0h) == h) ? mine : oth;
        const float4* __restrict__ wr =
            (const float4*)(w1 + (size_t)c * F1 + h * F1h);
#pragma unroll
        for (int j4 = 0; j4 < F1h / 4; ++j4) {
            const float4 w = wr[j4];
            acc1[4 * j4 + 0] = fmaf(xc, w.x, acc1[4 * j4 + 0]);
            acc1[4 * j4 + 1] = fmaf(xc, w.y, acc1[4 * j4 + 1]);
            acc1[4 * j4 + 2] = fmaf(xc, w.z, acc1[4 * j4 + 2]);
            acc1[4 * j4 + 3] = fmaf(xc, w.w, acc1[4 * j4 + 3]);
        }
    }
#pragma unroll
    for (int j = 0; j < F1h; ++j) acc1[j] = fmaxf(acc1[j], 0.0f);

    // ---- layer 3 (chunks of 16 of this half's F2h) + pool + publish ----
#pragma unroll 1
    for (int ch = 0; ch < F2h / 16; ++ch) {
        float acc[16];
#pragma unroll
        for (int j = 0; j < 16; ++j) acc[j] = 0.0f;
#pragma unroll
        for (int c = 0; c < F1; ++c) {
            const float mine = acc1[c % F1h];
            const float oth  = shflx1(mine);
            const float xc   = ((c / F1h) == h) ? mine : oth;
            const float4* __restrict__ wr =
                (const float4*)(w2 + (size_t)c * F2 + h * F2h + ch * 16);
#pragma unroll
            for (int j4 = 0; j4 < 4; ++j4) {
                const float4 w = wr[j4];
                acc[4 * j4 + 0] = fmaf(xc, w.x, acc[4 * j4 + 0]);
                acc[4 * j4 + 1] = fmaf(xc, w.y, acc[4 * j4 + 1]);
                acc[4 * j4 + 2] = fmaf(xc, w.z, acc[4 * j4 + 2]);
                acc[4 * j4 + 3] = fmaf(xc, w.w, acc[4 * j4 + 3]);
            }
        }
#pragma unroll
        for (int j = 0; j < 16; ++j) acc[j] = fmaxf(acc[j], 0.0f);
        // max-pool over neighbors: lane bits 1..5 (h stays separate)
#pragma unroll
        for (int off = 2; off < 64; off <<= 1) {
#pragma unroll
            for (int j = 0; j < 16; ++j)
                acc[j] = fmaxf(acc[j], __shfl_xor(acc[j], off));
        }
        if (nbl == 0) {
#pragma unroll
            for (int j = 0; j < 16; ++j)
                pool[qlocal][wq][h][ch * 16 + j] = acc[j];
        }
    }
    __syncthreads();

    // ---- cross-wave pool reduce + coalesced store ----
    for (int t = tid; t < NQ * F2; t += 256) {
        const int ql = t / F2, chn = t % F2;
        const int hh = chn / F2h, j = chn % F2h;
        float v = pool[ql][0][hh][j];
#pragma unroll
        for (int w = 1; w < WQ; ++w)
            v = fmaxf(v, pool[ql][w][hh][j]);
        out1[(size_t)(blockIdx.x * NQ + ql) * 320 + CH_OFF + chn] = v;
    }
}

// ---------------------------------------------------------------------------
// Round-7 fused-stream kernel, kept for scale 0 (K=16; small live set).
// ---------------------------------------------------------------------------
template <int CIN, int FOUT, int CH, int K>
__device__ __forceinline__ void dense_pool_store(const float* __restrict__ W,
                                                 const float* __restrict__ in,
                                                 int k, float* __restrict__ outp)
{
#pragma unroll 1
    for (int ch = 0; ch < FOUT / CH; ++ch) {
        const float* __restrict__ Wc = W + ch * CH;
        float acc[CH];
#pragma unroll
        for (int j = 0; j < CH; ++j) acc[j] = 0.0f;
#pragma unroll
        for (int c = 0; c < CIN; ++c) {
            const float xc = in[c];
#pragma unroll
            for (int j = 0; j < CH; ++j)
                acc[j] = fmaf(xc, Wc[c * FOUT + j], acc[j]);
        }
#pragma unroll
        for (int j = 0; j < CH; ++j) acc[j] = fmaxf(acc[j], 0.0f);
#pragma unroll
        for (int off = 1; off < K; off <<= 1) {
#pragma unroll
            for (int j = 0; j < CH; ++j)
                acc[j] = fmaxf(acc[j], __shfl_xor(acc[j], off));
        }
        if (k == 0) {
            float4* o = (float4*)(outp + ch * CH);
#pragma unroll
            for (int j = 0; j < CH / 4; ++j)
                o[j] = make_float4(acc[4 * j + 0], acc[4 * j + 1],
                                   acc[4 * j + 2], acc[4 * j + 3]);
        }
    }
}

template <int K, int F0, int F1, int F2, int CH_OFF, int NT>
__global__ __launch_bounds__(NT, 1) void sa_kernel(
    const float* __restrict__ xyz,
    const float* __restrict__ points,
    const float* __restrict__ newxyz,
    const float* __restrict__ w0,
    const float* __restrict__ w1,
    const float* __restrict__ w2,
    float* __restrict__ out1,
    float r2)
{
    constexpr int QPW = 64 / K;
    constexpr int NW  = NT / 64;
    constexpr unsigned long long KMASK =
        (K == 64) ? ~0ULL : ((1ULL << K) - 1ULL);

    __shared__ int slist[NT];

    const int tid  = threadIdx.x;
    const int lane = tid & 63;
    const int wid  = tid >> 6;
    const int k    = lane & (K - 1);
    const int qsub = lane / K;
    const int qid  = (blockIdx.x * NW + wid) * QPW + qsub;
    const int b    = qid >> 10;

    const float qx = newxyz[(size_t)qid * 3 + 0];
    const float qy = newxyz[(size_t)qid * 3 + 1];
    const float qz = newxyz[(size_t)qid * 3 + 2];
    const float* bxyz = xyz + (size_t)b * NPTS * 3;

    int cnt = 0;
    const int gbase = (wid * QPW + qsub) * K;
    for (int c0 = 0; c0 < NPTS; c0 += K) {
        bool hit = false;
        const int p = c0 + k;
        if (cnt < K) {
            const float dx = __fsub_rn(qx, bxyz[3 * p]);
            const float dy = __fsub_rn(qy, bxyz[3 * p + 1]);
            const float dz = __fsub_rn(qz, bxyz[3 * p + 2]);
            const float d2 = __fadd_rn(__fadd_rn(__fmul_rn(dx, dx), __fmul_rn(dy, dy)),
                                       __fmul_rn(dz, dz));
            hit = d2 < r2;
        }
        const unsigned long long bal = __ballot(hit);
        const unsigned long long gm  = (bal >> (qsub * K)) & KMASK;
        const int pre = __popcll(gm & ((1ULL << k) - 1ULL));
        const int pos = cnt + pre;
        if (hit && pos < K) slist[gbase + pos] = p;
        cnt = min(cnt + (int)__popcll(gm), K);
        if (__all(cnt >= K)) break;
    }
    const int nbr = slist[gbase + ((k < cnt) ? k : 0)];

    float a0r[19];
    {
        const float4* prow = (const float4*)(points + ((size_t)b * NPTS + nbr) * 16);
        const float4 p0 = prow[0], p1 = prow[1], p2 = prow[2], p3 = prow[3];
        a0r[0]  = p0.x; a0r[1]  = p0.y; a0r[2]  = p0.z; a0r[3]  = p0.w;
        a0r[4]  = p1.x; a0r[5]  = p1.y; a0r[6]  = p1.z; a0r[7]  = p1.w;
        a0r[8]  = p2.x; a0r[9]  = p2.y; a0r[10] = p2.z; a0r[11] = p2.w;
        a0r[12] = p3.x; a0r[13] = p3.y; a0r[14] = p3.z; a0r[15] = p3.w;
        a0r[16] = __fsub_rn(bxyz[3 * nbr],     qx);
        a0r[17] = __fsub_rn(bxyz[3 * nbr + 1], qy);
        a0r[18] = __fsub_rn(bxyz[3 * nbr + 2], qz);
    }

    float acc1[F1];
#pragma unroll
    for (int f = 0; f < F1; ++f) acc1[f] = 0.0f;

#pragma unroll 1
    for (int ch = 0; ch < F0 / 16; ++ch) {
        const float* __restrict__ W0c = w0 + ch * 16;
        float t[16];
#pragma unroll
        for (int j = 0; j < 16; ++j) t[j] = 0.0f;
#pragma unroll
        for (int c = 0; c < 19; ++c) {
            const float xc = a0r[c];
#pragma unroll
            for (int j = 0; j < 16; ++j)
                t[j] = fmaf(xc, W0c[c * F0 + j], t[j]);
        }
#pragma unroll
        for (int j = 0; j < 16; ++j) t[j] = fmaxf(t[j], 0.0f);

        const float* __restrict__ W1c = w1 + (size_t)ch * 16 * F1;
#pragma unroll
        for (int i = 0; i < 16; ++i) {
            const float xi = t[i];
#pragma unroll
            for (int f = 0; f < F1; ++f)
                acc1[f] = fmaf(xi, W1c[i * F1 + f], acc1[f]);
        }
    }
#pragma unroll
    for (int f = 0; f < F1; ++f) acc1[f] = fmaxf(acc1[f], 0.0f);

    dense_pool_store<F1, F2, 16, K>(w2, acc1, k,
                                    out1 + (size_t)qid * 320 + CH_OFF);
}

// ---------------------------------------------------------------------------
extern "C" void kernel_launch(void* const* d_in, const int* in_sizes, int n_in,
                              void* d_out, int out_size, void* d_ws, size_t ws_size,
                              hipStream_t stream)
{
    const float* xyz    = (const float*)d_in[0];
    const float* points = (const float*)d_in[1];
    const float* w00 = (const float*)d_in[2];
    const float* w01 = (const float*)d_in[3];
    const float* w02 = (const float*)d_in[4];
    const float* w10 = (const float*)d_in[5];
    const float* w11 = (const float*)d_in[6];
    const float* w12 = (const float*)d_in[7];
    const float* w20 = (const float*)d_in[8];
    const float* w21 = (const float*)d_in[9];
    const float* w22 = (const float*)d_in[10];

    float* out       = (float*)d_out;
    float* out_nxyz  = out;                       // 16*1024*3   = 49152
    float* out_feat  = out + 49152;               // 16*1024*320 = 5242880
    float* out_idxf  = out + 49152 + 5242880;     // 16*1024     = 16384

    fps_kernel<<<BATCH, 256, 0, stream>>>(xyz, out_nxyz, out_idxf);

    // scale 0: r=0.1, K=16, MLP 19->32->32->64, CH_OFF 0 (round-7 path)
    sa_kernel<16, 32, 32, 64, 0, 256><<<1024, 256, 0, stream>>>(
        xyz, points, out_nxyz, w00, w01, w02, out_feat, (float)(0.1 * 0.1));
    // scale 1: r=0.2, K=32, MLP 19->64->64->128, CH_OFF 64 (pair-split)
    sa_pair_kernel<32, 64, 64, 128, 64><<<4096, 256, 0, stream>>>(
        xyz, points, out_nxyz, w10, w11, w12, out_feat, (float)(0.2 * 0.2));
    // scale 2: r=0.4, K=64, MLP 19->64->96->128, CH_OFF 192 (pair-split)
    sa_pair_kernel<64, 64, 96, 128, 192><<<8192, 256, 0, stream>>>(
        xyz, points, out_nxyz, w20, w21, w22, out_feat, (float)(0.4 * 0.4));
}

// Round 10
// 2164.871 us; speedup vs baseline: 2.7356x; 2.7356x over previous
//
#include <hip/hip_runtime.h>

#define NPTS 4096
#define NPT  1024
#define BATCH 16

// ---------------------------------------------------------------------------
// DPP helpers: VALU-speed cross-lane max-reduce on a packed u64 key
// (float_bits(dist)<<32)|~idx. dist>=0 -> float bits monotone; ~idx breaks
// ties toward the smaller index (== jnp.argmax first-max). Identity 0 loses
// to every real key (lo = ~p != 0 for p <= 4095).
// ---------------------------------------------------------------------------
template <int CTRL>
__device__ __forceinline__ void dpp_keymax_xyz(unsigned long long& key,
                                               float& x, float& y, float& z)
{
    const int klo = (int)(unsigned int)key;
    const int khi = (int)(unsigned int)(key >> 32);
    const int nlo = __builtin_amdgcn_update_dpp(0, klo, CTRL, 0xF, 0xF, false);
    const int nhi = __builtin_amdgcn_update_dpp(0, khi, CTRL, 0xF, 0xF, false);
    const int nx  = __builtin_amdgcn_update_dpp(0, __float_as_int(x), CTRL, 0xF, 0xF, false);
    const int ny  = __builtin_amdgcn_update_dpp(0, __float_as_int(y), CTRL, 0xF, 0xF, false);
    const int nz  = __builtin_amdgcn_update_dpp(0, __float_as_int(z), CTRL, 0xF, 0xF, false);
    const unsigned long long ok =
        ((unsigned long long)(unsigned int)nhi << 32) | (unsigned int)nlo;
    const bool gt = ok > key;
    key = gt ? ok : key;
    x = gt ? __int_as_float(nx) : x;
    y = gt ? __int_as_float(ny) : y;
    z = gt ? __int_as_float(nz) : z;
}

// ---------------------------------------------------------------------------
// Farthest point sampling: one block (256 thr / 4 waves) per batch element.
// Branchless local argmax with coord tracking (3 cndmask/pt); wave reduce via
// DPP row_shr:1/2/4/8 + row_bcast15/31 CARRYING the winner's coords (no
// post-reduce LDS fetch on the serial critical path). Cross-wave: publish
// {key,x,y,z} per wave, reduce 4->1 with quad_perm DPP stages. No global
// stores inside the loop. Distance math identical to reference
// (no-FMA ((dx*dx+dy*dy)+dz*dz), fminf).
// ---------------------------------------------------------------------------
__global__ __launch_bounds__(256) void fps_kernel(
    const float* __restrict__ xyz,
    float* __restrict__ out_nxyz,
    float* __restrict__ out_idxf)
{
    __shared__ float sx[NPTS], sy[NPTS], sz[NPTS];
    __shared__ float4 pr0[2][4];    // {key_lo, key_hi, x, y} per wave
    __shared__ float  pr1[2][4];    // z per wave
    __shared__ int sidx[NPT];

    const int tid  = threadIdx.x;
    const int b    = blockIdx.x;
    const int lane = tid & 63;
    const int wid  = tid >> 6;

    const float* bx = xyz + (size_t)b * NPTS * 3;
    for (int p = tid; p < NPTS; p += 256) {
        sx[p] = bx[3 * p];
        sy[p] = bx[3 * p + 1];
        sz[p] = bx[3 * p + 2];
    }
    if (tid == 0) sidx[0] = 0;
    __syncthreads();

    float rx[16], ry[16], rz[16], dist[16];
#pragma unroll
    for (int j = 0; j < 16; ++j) {
        const int p = tid + j * 256;
        rx[j] = sx[p];
        ry[j] = sy[p];
        rz[j] = sz[p];
        dist[j] = 1e10f;
    }

    float lx = sx[0], ly = sy[0], lz = sz[0];

    for (int step = 1; step < NPT; ++step) {
        // ---- local 16-point update + branchless argmax w/ coord track ----
        float bv = -1.0f;
        int   bp = 0;
        float bxl = 0.0f, byl = 0.0f, bzl = 0.0f;
#pragma unroll
        for (int j = 0; j < 16; ++j) {
            const int p = tid + j * 256;
            const float dx = __fsub_rn(rx[j], lx);
            const float dy = __fsub_rn(ry[j], ly);
            const float dz = __fsub_rn(rz[j], lz);
            const float d  = __fadd_rn(__fadd_rn(__fmul_rn(dx, dx), __fmul_rn(dy, dy)),
                                       __fmul_rn(dz, dz));
            const float nd = fminf(dist[j], d);
            dist[j] = nd;
            const bool gt = nd > bv;     // strict: first max within thread
            bv  = gt ? nd    : bv;
            bp  = gt ? p     : bp;
            bxl = gt ? rx[j] : bxl;
            byl = gt ? ry[j] : byl;
            bzl = gt ? rz[j] : bzl;
        }
        unsigned long long key =
            ((unsigned long long)__float_as_uint(bv) << 32) |
            (unsigned int)(~bp);

        // ---- wave max-reduce via DPP, coords travel with the key ----
        dpp_keymax_xyz<0x111>(key, bxl, byl, bzl);   // row_shr:1
        dpp_keymax_xyz<0x112>(key, bxl, byl, bzl);   // row_shr:2
        dpp_keymax_xyz<0x114>(key, bxl, byl, bzl);   // row_shr:4
        dpp_keymax_xyz<0x118>(key, bxl, byl, bzl);   // row_shr:8
        dpp_keymax_xyz<0x142>(key, bxl, byl, bzl);   // row_bcast15
        dpp_keymax_xyz<0x143>(key, bxl, byl, bzl);   // row_bcast31 -> lane63

        const int par = step & 1;
        if (lane == 63) {
            pr0[par][wid] = make_float4(
                __int_as_float((int)(unsigned int)key),
                __int_as_float((int)(unsigned int)(key >> 32)),
                bxl, byl);
            pr1[par][wid] = bzl;
        }
        __syncthreads();

        // ---- cross-wave: read record lane&3, quad_perm reduce 4 -> 1 ----
        const float4 r   = pr0[par][lane & 3];
        const float  rzz = pr1[par][lane & 3];
        unsigned long long gkey =
            ((unsigned long long)(unsigned int)__float_as_int(r.y) << 32) |
            (unsigned int)__float_as_int(r.x);
        float gx = r.z, gy = r.w, gz = rzz;
        dpp_keymax_xyz<0xB1>(gkey, gx, gy, gz);   // quad_perm xor1
        dpp_keymax_xyz<0x4E>(gkey, gx, gy, gz);   // quad_perm xor2

        lx = gx; ly = gy; lz = gz;
        if (tid == 0) sidx[step] = (int)(~(unsigned int)gkey);  // LDS only
        // single barrier per step: next step writes the other parity buffer.
    }
    __syncthreads();

    for (int s = tid; s < NPT; s += 256) {
        const int ix = sidx[s];
        out_idxf[b * NPT + s] = (float)ix;
        out_nxyz[(size_t)(b * NPT + s) * 3 + 0] = sx[ix];
        out_nxyz[(size_t)(b * NPT + s) * 3 + 1] = sy[ix];
        out_nxyz[(size_t)(b * NPT + s) * 3 + 2] = sz[ix];
    }
}

// ---------------------------------------------------------------------------
// Final layer: output channels in chunks of CH inside a ROLLED chunk loop
// (acc regs reused, all register indices static; only pointers are runtime).
// relu + K-lane max-pool butterfly + store per chunk.
// ---------------------------------------------------------------------------
template <int CIN, int FOUT, int CH, int K>
__device__ __forceinline__ void dense_pool_store(const float* __restrict__ W,
                                                 const float* __restrict__ in,
                                                 int k, float* __restrict__ outp)
{
#pragma unroll 1
    for (int ch = 0; ch < FOUT / CH; ++ch) {
        const float* __restrict__ Wc = W + ch * CH;
        float acc[CH];
#pragma unroll
        for (int j = 0; j < CH; ++j) acc[j] = 0.0f;
#pragma unroll
        for (int c = 0; c < CIN; ++c) {
            const float xc = in[c];
#pragma unroll
            for (int j = 0; j < CH; ++j)
                acc[j] = fmaf(xc, Wc[c * FOUT + j], acc[j]);
        }
#pragma unroll
        for (int j = 0; j < CH; ++j) acc[j] = fmaxf(acc[j], 0.0f);
#pragma unroll
        for (int off = 1; off < K; off <<= 1) {
#pragma unroll
            for (int j = 0; j < CH; ++j)
                acc[j] = fmaxf(acc[j], __shfl_xor(acc[j], off));
        }
        if (k == 0) {
            float4* o = (float4*)(outp + ch * CH);
#pragma unroll
            for (int j = 0; j < CH / 4; ++j)
                o[j] = make_float4(acc[4 * j + 0], acc[4 * j + 1],
                                   acc[4 * j + 2], acc[4 * j + 3]);
        }
    }
}

// ---------------------------------------------------------------------------
// Per-scale: ball query + gather + 3-layer MLP + max-pool (round-7 fused
// stream). amdgpu_waves_per_eu(1,2): direct the allocator to target <=2
// waves/EU so the ~130-float live set (acc1[F1]+t+a0r) fits in ARCH VGPRs
// (VALU-addressable) instead of being paged through AGPRs with
// v_accvgpr_read/write copies -- round 7's occupancy arithmetic showed
// ~190 unified regs/wave at VGPR_Count=72, i.e. ~120 AGPRs + copy traffic
// (the measured 2.1x VALU-issue inflation over the FMA floor).
// Accumulation order (c ascending per output) bit-identical to reference.
// ---------------------------------------------------------------------------
template <int K, int F0, int F1, int F2, int CH_OFF, int NT>
__global__
__attribute__((amdgpu_waves_per_eu(1, 2)))
__launch_bounds__(NT) void sa_kernel(
    const float* __restrict__ xyz,
    const float* __restrict__ points,
    const float* __restrict__ newxyz,
    const float* __restrict__ w0,
    const float* __restrict__ w1,
    const float* __restrict__ w2,
    float* __restrict__ out1,
    float r2)
{
    constexpr int QPW = 64 / K;
    constexpr int NW  = NT / 64;
    constexpr unsigned long long KMASK =
        (K == 64) ? ~0ULL : ((1ULL << K) - 1ULL);

    __shared__ int slist[NT];

    const int tid  = threadIdx.x;
    const int lane = tid & 63;
    const int wid  = tid >> 6;
    const int k    = lane & (K - 1);
    const int qsub = lane / K;
    const int qid  = (blockIdx.x * NW + wid) * QPW + qsub;
    const int b    = qid >> 10;

    const float qx = newxyz[(size_t)qid * 3 + 0];
    const float qy = newxyz[(size_t)qid * 3 + 1];
    const float qz = newxyz[(size_t)qid * 3 + 2];
    const float* bxyz = xyz + (size_t)b * NPTS * 3;

    // ---- ball query: first K in-ball indices in ascending order ----
    int cnt = 0;
    const int gbase = (wid * QPW + qsub) * K;
    for (int c0 = 0; c0 < NPTS; c0 += K) {
        bool hit = false;
        const int p = c0 + k;
        if (cnt < K) {
            const float dx = __fsub_rn(qx, bxyz[3 * p]);
            const float dy = __fsub_rn(qy, bxyz[3 * p + 1]);
            const float dz = __fsub_rn(qz, bxyz[3 * p + 2]);
            const float d2 = __fadd_rn(__fadd_rn(__fmul_rn(dx, dx), __fmul_rn(dy, dy)),
                                       __fmul_rn(dz, dz));
            hit = d2 < r2;
        }
        const unsigned long long bal = __ballot(hit);
        const unsigned long long gm  = (bal >> (qsub * K)) & KMASK;
        const int pre = __popcll(gm & ((1ULL << k) - 1ULL));
        const int pos = cnt + pre;
        if (hit && pos < K) slist[gbase + pos] = p;
        cnt = min(cnt + (int)__popcll(gm), K);
        if (__all(cnt >= K)) break;
    }
    const int nbr = slist[gbase + ((k < cnt) ? k : 0)];

    // ---- gather: 16 point features + 3 relative xyz into REGISTERS ----
    float a0r[19];
    {
        const float4* prow = (const float4*)(points + ((size_t)b * NPTS + nbr) * 16);
        const float4 p0 = prow[0], p1 = prow[1], p2 = prow[2], p3 = prow[3];
        a0r[0]  = p0.x; a0r[1]  = p0.y; a0r[2]  = p0.z; a0r[3]  = p0.w;
        a0r[4]  = p1.x; a0r[5]  = p1.y; a0r[6]  = p1.z; a0r[7]  = p1.w;
        a0r[8]  = p2.x; a0r[9]  = p2.y; a0r[10] = p2.z; a0r[11] = p2.w;
        a0r[12] = p3.x; a0r[13] = p3.y; a0r[14] = p3.z; a0r[15] = p3.w;
        a0r[16] = __fsub_rn(bxyz[3 * nbr],     qx);
        a0r[17] = __fsub_rn(bxyz[3 * nbr + 1], qy);
        a0r[18] = __fsub_rn(bxyz[3 * nbr + 2], qz);
    }

    // ---- fused layer1 + layer2 stream ----
    float acc1[F1];
#pragma unroll
    for (int f = 0; f < F1; ++f) acc1[f] = 0.0f;

#pragma unroll 1
    for (int ch = 0; ch < F0 / 16; ++ch) {
        const float* __restrict__ W0c = w0 + ch * 16;
        float t[16];
#pragma unroll
        for (int j = 0; j < 16; ++j) t[j] = 0.0f;
#pragma unroll
        for (int c = 0; c < 19; ++c) {
            const float xc = a0r[c];
#pragma unroll
            for (int j = 0; j < 16; ++j)
                t[j] = fmaf(xc, W0c[c * F0 + j], t[j]);
        }
#pragma unroll
        for (int j = 0; j < 16; ++j) t[j] = fmaxf(t[j], 0.0f);

        const float* __restrict__ W1c = w1 + (size_t)ch * 16 * F1;
#pragma unroll
        for (int i = 0; i < 16; ++i) {
            const float xi = t[i];
#pragma unroll
            for (int f = 0; f < F1; ++f)
                acc1[f] = fmaf(xi, W1c[i * F1 + f], acc1[f]);
        }
    }
#pragma unroll
    for (int f = 0; f < F1; ++f) acc1[f] = fmaxf(acc1[f], 0.0f);

    dense_pool_store<F1, F2, 16, K>(w2, acc1, k,
                                    out1 + (size_t)qid * 320 + CH_OFF);
}

// ---------------------------------------------------------------------------
extern "C" void kernel_launch(void* const* d_in, const int* in_sizes, int n_in,
                              void* d_out, int out_size, void* d_ws, size_t ws_size,
                              hipStream_t stream)
{
    const float* xyz    = (const float*)d_in[0];
    const float* points = (const float*)d_in[1];
    const float* w00 = (const float*)d_in[2];
    const float* w01 = (const float*)d_in[3];
    const float* w02 = (const float*)d_in[4];
    const float* w10 = (const float*)d_in[5];
    const float* w11 = (const float*)d_in[6];
    const float* w12 = (const float*)d_in[7];
    const float* w20 = (const float*)d_in[8];
    const float* w21 = (const float*)d_in[9];
    const float* w22 = (const float*)d_in[10];

    float* out       = (float*)d_out;
    float* out_nxyz  = out;                       // 16*1024*3   = 49152
    float* out_feat  = out + 49152;               // 16*1024*320 = 5242880
    float* out_idxf  = out + 49152 + 5242880;     // 16*1024     = 16384

    fps_kernel<<<BATCH, 256, 0, stream>>>(xyz, out_nxyz, out_idxf);

    // scale 0: r=0.1, K=16, MLP 19->32->32->64, CH_OFF 0
    sa_kernel<16, 32, 32, 64, 0, 256><<<1024, 256, 0, stream>>>(
        xyz, points, out_nxyz, w00, w01, w02, out_feat, (float)(0.1 * 0.1));
    // scale 1: r=0.2, K=32, MLP 19->64->64->128, CH_OFF 64
    sa_kernel<32, 64, 64, 128, 64, 128><<<4096, 128, 0, stream>>>(
        xyz, points, out_nxyz, w10, w11, w12, out_feat, (float)(0.2 * 0.2));
    // scale 2: r=0.4, K=64, MLP 19->64->96->128, CH_OFF 192
    sa_kernel<64, 64, 96, 128, 192, 128><<<8192, 128, 0, stream>>>(
        xyz, points, out_nxyz, w20, w21, w22, out_feat, (float)(0.4 * 0.4));
}